// Round 8
// baseline (448.254 us; speedup 1.0000x reference)
//
#include <hip/hip_runtime.h>
#include <stdint.h>

#define NPOLAR 1024
#define KT 512
#define BLOCK 256
#define ROWS 32            // rows per block
#define PKP 18             // packed stream row pitch: 16 words + parity + zero pad
#define XLP 36             // encoded row pitch (16B-aligned uint4 slots)

__device__ __forceinline__ uint32_t fbit(float f) {
    return (__float_as_uint(f) >> 29) & 1u;   // inputs are exactly 0.0f / 1.0f
}

// ============ Fused: ballot-pack + CRC + scatter + butterfly + permuted expand ============
__global__ __launch_bounds__(BLOCK) void polar_fused_kernel(
    const float* __restrict__ u,
    const float* __restrict__ crc_gen,
    const int* __restrict__ info_pos,
    const int* __restrict__ perm_out,
    float* __restrict__ out)
{
    __shared__ uint32_t pk[ROWS * PKP];   // packed info stream per row (+parity,+0)
    __shared__ uint32_t xl[ROWS * XLP];   // encoded rows
    __shared__ uint32_t gc[11 * 16];      // packed CRC generator columns
    __shared__ uint32_t mw[32];           // info-bit mask per dest word
    __shared__ uint32_t cw[32];           // stream rank (bits before word w)

    const int t   = threadIdx.x;
    const int blk = blockIdx.x;
    const int r   = t >> 3;               // row within block (0..31)
    const int q   = t & 7;                // 8-way part within row
    const int w   = t >> 6;               // wave id (0..3)
    const int l   = t & 63;               // lane id

    if (t < 32) mw[t] = 0;
    __syncthreads();

    // ---- per-block tables (uniform, L2-hot) ----
    for (int i = t; i < 523; i += BLOCK) {
        int pos = info_pos[i];
        atomicOr(&mw[pos >> 5], 1u << (pos & 31));
    }
    if (t < 176) {
        int j = t / 16, wd = t % 16;
        uint32_t g = 0;
        #pragma unroll
        for (int i = 0; i < 32; ++i)
            g |= fbit(crc_gen[(32 * wd + i) * 11 + j]) << i;
        gc[j * 16 + wd] = g;
    }

    // ---- Phase A: ballot pack. Wave w reads its 8 rows (16 KB) sequentially. ----
    // ballot j covers u_blk[4096w + 64j + lane]; owner lane == j; result = words
    // {2q, 2q+1} of row r for the owning thread (verified: owner lane 8*(j>>3)+(j&7)=j).
    uint32_t uwA = 0, uwB = 0;
    {
        const float* ub = u + (size_t)blk * (ROWS * KT) + (size_t)w * 4096 + l;
        #pragma unroll
        for (int j = 0; j < 64; ++j) {
            float f = ub[(size_t)j * 64];
            uint64_t b = __ballot(f != 0.0f);
            if (l == j) { uwA = (uint32_t)b; uwB = (uint32_t)(b >> 32); }
        }
    }
    __syncthreads();   // mw, gc ready (phase A itself is register-only)

    // ---- ranks (needs mw) ----
    if (t < 32) {
        uint32_t c = 0;
        for (int v = 0; v < t; ++v) c += __popc(mw[v]);
        cw[t] = c;
    }

    // ---- Phase B: CRC-11 from registers, 8-way split per row ----
    {
        uint32_t par = 0;
        #pragma unroll
        for (int j = 0; j < 11; ++j) {
            uint32_t acc = (uwA & gc[j * 16 + 2 * q]) ^ (uwB & gc[j * 16 + 2 * q + 1]);
            par |= (uint32_t)(__popc(acc) & 1) << j;
        }
        par ^= __shfl_xor(par, 1);
        par ^= __shfl_xor(par, 2);
        par ^= __shfl_xor(par, 4);
        // publish the packed stream for the cross-lane scatter reads
        pk[r * PKP + 2 * q]     = uwA;
        pk[r * PKP + 2 * q + 1] = uwB;
        if (q == 0) pk[r * PKP + 16] = par;
        if (q == 1) pk[r * PKP + 17] = 0;
    }
    __syncthreads();   // pk + cw ready

    // ---- Phase C: scatter via mask/rank (4 dest words per thread) ----
    uint32_t xr[4];
    {
        const uint32_t* row = &pk[r * PKP];
        #pragma unroll
        for (int j = 0; j < 4; ++j) {
            int wd = 4 * q + j;
            uint32_t m = mw[wd];
            uint32_t c = cw[wd];
            int k = c >> 5, sh = c & 31;
            uint64_t win = (((uint64_t)row[k + 1] << 32) | row[k]) >> sh;
            uint32_t x;
            if (m == 0xFFFFFFFFu) {
                x = (uint32_t)win;
            } else {
                x = 0;
                uint32_t wv = (uint32_t)win;
                while (m) {
                    int b = __builtin_ctz(m);
                    m &= m - 1;
                    x |= (wv & 1u) << b;
                    wv >>= 1;
                }
            }
            xr[j] = x;
        }
    }

    // ---- Phase D: 10-stage butterfly (in-word, in-thread, cross-thread) ----
    #pragma unroll
    for (int j = 0; j < 4; ++j) {
        uint32_t v = xr[j];
        v ^= (v >> 1)  & 0x55555555u;
        v ^= (v >> 2)  & 0x33333333u;
        v ^= (v >> 4)  & 0x0F0F0F0Fu;
        v ^= (v >> 8)  & 0x00FF00FFu;
        v ^= (v >> 16) & 0x0000FFFFu;
        xr[j] = v;
    }
    xr[0] ^= xr[1]; xr[2] ^= xr[3];
    xr[0] ^= xr[2]; xr[1] ^= xr[3];
    #pragma unroll
    for (int j = 0; j < 4; ++j) {
        uint32_t p;
        p = __shfl_xor(xr[j], 1); if ((q & 1) == 0) xr[j] ^= p;
        p = __shfl_xor(xr[j], 2); if ((q & 2) == 0) xr[j] ^= p;
        p = __shfl_xor(xr[j], 4); if ((q & 4) == 0) xr[j] ^= p;
    }
    *reinterpret_cast<uint4*>(&xl[r * XLP + 4 * q]) = make_uint4(xr[0], xr[1], xr[2], xr[3]);
    __syncthreads();

    // ---- Phase E: permuted expansion, coalesced float4 stores ----
    const int4 pv = reinterpret_cast<const int4*>(perm_out)[t];
    const int a0 = pv.x >> 5; const uint32_t m0 = 1u << (pv.x & 31);
    const int a1 = pv.y >> 5; const uint32_t m1 = 1u << (pv.y & 31);
    const int a2 = pv.z >> 5; const uint32_t m2 = 1u << (pv.z & 31);
    const int a3 = pv.w >> 5; const uint32_t m3 = 1u << (pv.w & 31);

    float4* outv = reinterpret_cast<float4*>(out) + (size_t)blk * (ROWS * (NPOLAR / 4)) + t;
    #pragma unroll
    for (int k = 0; k < ROWS; ++k) {
        const uint32_t* rowp = &xl[k * XLP];
        float4 o;
        o.x = (rowp[a0] & m0) ? 1.0f : 0.0f;
        o.y = (rowp[a1] & m1) ? 1.0f : 0.0f;
        o.z = (rowp[a2] & m2) ? 1.0f : 0.0f;
        o.w = (rowp[a3] & m3) ? 1.0f : 0.0f;
        outv[(size_t)k * (NPOLAR / 4)] = o;
    }
}

extern "C" void kernel_launch(void* const* d_in, const int* in_sizes, int n_in,
                              void* d_out, int out_size, void* d_ws, size_t ws_size,
                              hipStream_t stream) {
    const float* u        = (const float*)d_in[0];
    const float* crc_gen  = (const float*)d_in[1];
    const int*   info_pos = (const int*)d_in[2];
    // d_in[3] = ind_gather (butterfly structure derived analytically; unused)
    const int*   perm_out = (const int*)d_in[4];
    float* out = (float*)d_out;

    const int rows = in_sizes[0] / KT;          // 65536
    const int grid = rows / ROWS;               // 2048 blocks -> 8 blocks/CU

    // PROBE: launch TWICE (idempotent — same output both times, no ws use).
    // dur8 = F + 2T. Next round launches once: dur9 = F + T.
    //  => T = dur8 - dur9, F = 2*dur9 - dur8. Exact overhead/kernel decomposition.
    polar_fused_kernel<<<grid, BLOCK, 0, stream>>>(u, crc_gen, info_pos, perm_out, out);
    polar_fused_kernel<<<grid, BLOCK, 0, stream>>>(u, crc_gen, info_pos, perm_out, out);
}

// Round 9
// 369.776 us; speedup vs baseline: 1.2122x; 1.2122x over previous
//
#include <hip/hip_runtime.h>
#include <stdint.h>

#define NPOLAR 1024
#define KT 512
#define BLOCK 256
#define ROWS 32            // rows per block
#define PKP 18             // packed stream row pitch: 16 words + parity + zero pad
#define XLP 36             // encoded row pitch (16B-aligned uint4 slots)

__device__ __forceinline__ uint32_t fbit(float f) {
    return (__float_as_uint(f) >> 29) & 1u;   // inputs are exactly 0.0f / 1.0f
}

// ============ Fused: ballot-pack + CRC + scatter + butterfly + permuted expand ============
__global__ __launch_bounds__(BLOCK) void polar_fused_kernel(
    const float* __restrict__ u,
    const float* __restrict__ crc_gen,
    const int* __restrict__ info_pos,
    const int* __restrict__ perm_out,
    float* __restrict__ out)
{
    __shared__ uint32_t pk[ROWS * PKP];   // packed info stream per row (+parity,+0)
    __shared__ uint32_t xl[ROWS * XLP];   // encoded rows
    __shared__ uint32_t gc[11 * 16];      // packed CRC generator columns
    __shared__ uint32_t mw[32];           // info-bit mask per dest word
    __shared__ uint32_t cw[32];           // stream rank (bits before word w)

    const int t   = threadIdx.x;
    const int blk = blockIdx.x;
    const int r   = t >> 3;               // row within block (0..31)
    const int q   = t & 7;                // 8-way part within row
    const int w   = t >> 6;               // wave id (0..3)
    const int l   = t & 63;               // lane id

    if (t < 32) mw[t] = 0;
    __syncthreads();

    // ---- per-block tables (uniform, L2-hot) ----
    for (int i = t; i < 523; i += BLOCK) {
        int pos = info_pos[i];
        atomicOr(&mw[pos >> 5], 1u << (pos & 31));
    }
    if (t < 176) {
        int j = t / 16, wd = t % 16;
        uint32_t g = 0;
        #pragma unroll
        for (int i = 0; i < 32; ++i)
            g |= fbit(crc_gen[(32 * wd + i) * 11 + j]) << i;
        gc[j * 16 + wd] = g;
    }

    // ---- Phase A: ballot pack. Wave w reads its 8 rows (16 KB) sequentially. ----
    // ballot j covers u_blk[4096w + 64j + lane]; owner lane == j; result = words
    // {2q, 2q+1} of row r for the owning thread (verified: owner lane 8*(j>>3)+(j&7)=j).
    uint32_t uwA = 0, uwB = 0;
    {
        const float* ub = u + (size_t)blk * (ROWS * KT) + (size_t)w * 4096 + l;
        #pragma unroll
        for (int j = 0; j < 64; ++j) {
            float f = ub[(size_t)j * 64];
            uint64_t b = __ballot(f != 0.0f);
            if (l == j) { uwA = (uint32_t)b; uwB = (uint32_t)(b >> 32); }
        }
    }
    __syncthreads();   // mw, gc ready (phase A itself is register-only)

    // ---- ranks (needs mw) ----
    if (t < 32) {
        uint32_t c = 0;
        for (int v = 0; v < t; ++v) c += __popc(mw[v]);
        cw[t] = c;
    }

    // ---- Phase B: CRC-11 from registers, 8-way split per row ----
    {
        uint32_t par = 0;
        #pragma unroll
        for (int j = 0; j < 11; ++j) {
            uint32_t acc = (uwA & gc[j * 16 + 2 * q]) ^ (uwB & gc[j * 16 + 2 * q + 1]);
            par |= (uint32_t)(__popc(acc) & 1) << j;
        }
        par ^= __shfl_xor(par, 1);
        par ^= __shfl_xor(par, 2);
        par ^= __shfl_xor(par, 4);
        // publish the packed stream for the cross-lane scatter reads
        pk[r * PKP + 2 * q]     = uwA;
        pk[r * PKP + 2 * q + 1] = uwB;
        if (q == 0) pk[r * PKP + 16] = par;
        if (q == 1) pk[r * PKP + 17] = 0;
    }
    __syncthreads();   // pk + cw ready

    // ---- Phase C: scatter via mask/rank (4 dest words per thread) ----
    uint32_t xr[4];
    {
        const uint32_t* row = &pk[r * PKP];
        #pragma unroll
        for (int j = 0; j < 4; ++j) {
            int wd = 4 * q + j;
            uint32_t m = mw[wd];
            uint32_t c = cw[wd];
            int k = c >> 5, sh = c & 31;
            uint64_t win = (((uint64_t)row[k + 1] << 32) | row[k]) >> sh;
            uint32_t x;
            if (m == 0xFFFFFFFFu) {
                x = (uint32_t)win;
            } else {
                x = 0;
                uint32_t wv = (uint32_t)win;
                while (m) {
                    int b = __builtin_ctz(m);
                    m &= m - 1;
                    x |= (wv & 1u) << b;
                    wv >>= 1;
                }
            }
            xr[j] = x;
        }
    }

    // ---- Phase D: 10-stage butterfly (in-word, in-thread, cross-thread) ----
    #pragma unroll
    for (int j = 0; j < 4; ++j) {
        uint32_t v = xr[j];
        v ^= (v >> 1)  & 0x55555555u;
        v ^= (v >> 2)  & 0x33333333u;
        v ^= (v >> 4)  & 0x0F0F0F0Fu;
        v ^= (v >> 8)  & 0x00FF00FFu;
        v ^= (v >> 16) & 0x0000FFFFu;
        xr[j] = v;
    }
    xr[0] ^= xr[1]; xr[2] ^= xr[3];
    xr[0] ^= xr[2]; xr[1] ^= xr[3];
    #pragma unroll
    for (int j = 0; j < 4; ++j) {
        uint32_t p;
        p = __shfl_xor(xr[j], 1); if ((q & 1) == 0) xr[j] ^= p;
        p = __shfl_xor(xr[j], 2); if ((q & 2) == 0) xr[j] ^= p;
        p = __shfl_xor(xr[j], 4); if ((q & 4) == 0) xr[j] ^= p;
    }
    *reinterpret_cast<uint4*>(&xl[r * XLP + 4 * q]) = make_uint4(xr[0], xr[1], xr[2], xr[3]);
    __syncthreads();

    // ---- Phase E: permuted expansion, coalesced float4 stores ----
    const int4 pv = reinterpret_cast<const int4*>(perm_out)[t];
    const int a0 = pv.x >> 5; const uint32_t m0 = 1u << (pv.x & 31);
    const int a1 = pv.y >> 5; const uint32_t m1 = 1u << (pv.y & 31);
    const int a2 = pv.z >> 5; const uint32_t m2 = 1u << (pv.z & 31);
    const int a3 = pv.w >> 5; const uint32_t m3 = 1u << (pv.w & 31);

    float4* outv = reinterpret_cast<float4*>(out) + (size_t)blk * (ROWS * (NPOLAR / 4)) + t;
    #pragma unroll
    for (int k = 0; k < ROWS; ++k) {
        const uint32_t* rowp = &xl[k * XLP];
        float4 o;
        o.x = (rowp[a0] & m0) ? 1.0f : 0.0f;
        o.y = (rowp[a1] & m1) ? 1.0f : 0.0f;
        o.z = (rowp[a2] & m2) ? 1.0f : 0.0f;
        o.w = (rowp[a3] & m3) ? 1.0f : 0.0f;
        outv[(size_t)k * (NPOLAR / 4)] = o;
    }
}

extern "C" void kernel_launch(void* const* d_in, const int* in_sizes, int n_in,
                              void* d_out, int out_size, void* d_ws, size_t ws_size,
                              hipStream_t stream) {
    const float* u        = (const float*)d_in[0];
    const float* crc_gen  = (const float*)d_in[1];
    const int*   info_pos = (const int*)d_in[2];
    // d_in[3] = ind_gather (butterfly structure derived analytically; unused)
    const int*   perm_out = (const int*)d_in[4];
    float* out = (float*)d_out;

    const int rows = in_sizes[0] / KT;          // 65536
    const int grid = rows / ROWS;               // 2048 blocks -> 8 blocks/CU

    // PROBE part 2: single launch of the identical kernel.
    // R8 measured dur8 = F + 2T = 448.3. This run: dur9 = F + T.
    //  => T = dur8 - dur9, F = 2*dur9 - dur8.
    polar_fused_kernel<<<grid, BLOCK, 0, stream>>>(u, crc_gen, info_pos, perm_out, out);
}